// Round 3
// baseline (340.861 us; speedup 1.0000x reference)
//
#include <hip/hip_runtime.h>

typedef unsigned long long ull;
typedef float f4 __attribute__((ext_vector_type(4)));

__constant__ unsigned kSizes[16] = {
    6619u, 6637u, 6653u, 6659u, 6661u, 6673u, 6679u, 6689u,
    65521u, 65537u, 65539u, 65543u, 65551u, 65557u, 65563u, 65579u
};
// 1/size in double; h < 2^47 is exact in double, q_est = trunc(h*inv) is within
// +/-1 of floor(h/size) -> fix with two conditional corrections (exact).
__constant__ double kInv[16] = {
    1.0/6619.0,  1.0/6637.0,  1.0/6653.0,  1.0/6659.0,
    1.0/6661.0,  1.0/6673.0,  1.0/6679.0,  1.0/6689.0,
    1.0/65521.0, 1.0/65537.0, 1.0/65539.0, 1.0/65543.0,
    1.0/65551.0, 1.0/65557.0, 1.0/65563.0, 1.0/65579.0
};

// One thread per output float4: 32768 positions x 320 f4 = 10,485,760 threads.
// Each thread: compute its slot's hash index (double-recip mod), gather one
// float4 from the table row, nontemporal-store to out. Pure streaming shape;
// no LDS, no barriers, no inter-thread traffic.
__global__ __launch_bounds__(256)
void engram_fused_kernel(const int* __restrict__ ids,
                         const int* __restrict__ seeds,
                         const float* __restrict__ t0,  const float* __restrict__ t1,
                         const float* __restrict__ t2,  const float* __restrict__ t3,
                         const float* __restrict__ t4,  const float* __restrict__ t5,
                         const float* __restrict__ t6,  const float* __restrict__ t7,
                         const float* __restrict__ t8,  const float* __restrict__ t9,
                         const float* __restrict__ t10, const float* __restrict__ t11,
                         const float* __restrict__ t12, const float* __restrict__ t13,
                         const float* __restrict__ t14, const float* __restrict__ t15,
                         f4* __restrict__ out)
{
    const int tid = blockIdx.x * 256 + threadIdx.x;    // 0 .. 10485759
    const int pos = tid / 320;                          // const-div -> mul magic
    const int tx  = tid - pos * 320;                    // 0..319
    const int slot = tx / 20;                           // 0..15
    const int off  = tx - slot * 20;                    // f4 offset in 80-float row

    const int b = pos >> 12;
    const int s = pos & 4095;

    const int* row = ids + (b << 12);
    const int id0  = row[s];
    const int idm1 = (s >= 1) ? row[s - 1] : 0;         // left zero-pad per _ngrams
    const int idm2 = (s >= 2) ? row[s - 2] : 0;

    const int head = slot & 7;
    const ull sa = (ull)(unsigned)seeds[head];
    const ull sb = (ull)(unsigned)seeds[8 + head];
    const ull sc = (ull)(unsigned)seeds[16 + head];     // only used for slot>=8

    // bigram: [id(s-1), id(s)] . seeds[0:2];  trigram: [id(s-2..s)] . seeds[0:3]
    ull h;
    if (slot < 8) {
        h = ((ull)(unsigned)idm1 * sa) ^ ((ull)(unsigned)id0 * sb);
    } else {
        h = ((ull)(unsigned)idm2 * sa) ^ ((ull)(unsigned)idm1 * sb)
            ^ ((ull)(unsigned)id0 * sc);
    }
    // products < 2^47: xor stays non-negative; unsigned mod == JAX floored mod.
    const unsigned sz = kSizes[slot];
    ull q = (ull)((double)h * kInv[slot]);              // floor(h/sz) +/- 1
    long long r = (long long)(h - q * (ull)sz);
    if (r < 0)              r += sz;                    // q overestimated
    else if (r >= (long long)sz) r -= sz;               // q underestimated
    const unsigned ridx = (unsigned)r;

    const float* tabs[16] = {t0,t1,t2,t3,t4,t5,t6,t7,t8,t9,t10,t11,t12,t13,t14,t15};
    const f4* src = (const f4*)tabs[slot] + (size_t)ridx * 20 + off;
    __builtin_nontemporal_store(*src, out + tid);
}

extern "C" void kernel_launch(void* const* d_in, const int* in_sizes, int n_in,
                              void* d_out, int out_size, void* d_ws, size_t ws_size,
                              hipStream_t stream) {
    const int* ids   = (const int*)d_in[0];
    const int* seeds = (const int*)d_in[1];
    const float* t[16];
    for (int i = 0; i < 16; ++i) t[i] = (const float*)d_in[2 + i];

    // 10,485,760 threads / 256 = 40960 blocks
    engram_fused_kernel<<<dim3(40960), dim3(256), 0, stream>>>(
        ids, seeds,
        t[0], t[1], t[2], t[3], t[4], t[5], t[6], t[7],
        t[8], t[9], t[10], t[11], t[12], t[13], t[14], t[15],
        (f4*)d_out);
}